// Round 1
// baseline (296.832 us; speedup 1.0000x reference)
//
#include <hip/hip_runtime.h>
#include <stdint.h>

#define IN_F 4096
#define OUT_F 4096
#define NROWS 8192

typedef __attribute__((ext_vector_type(8))) short short8;
typedef __attribute__((ext_vector_type(4))) float floatx4;

static __device__ __forceinline__ unsigned short f2bf(float f) {
  union { float f; unsigned int u; } v; v.f = f;
  unsigned int u = v.u;
  return (unsigned short)((u + 0x7FFFu + ((u >> 16) & 1u)) >> 16);
}

// Catmull-Rom coefficients for output row o (matches reference exactly).
static __device__ __forceinline__ void cr_coeffs(int o, int& j, float& c0, float& c1,
                                                 float& c2, float& c3) {
  float ts = ((float)o / 4095.0f) * 8.0f;
  j = (int)floorf(ts);
  j = j < 1 ? 1 : (j > 6 ? 6 : j);
  float t = ts - (float)j;
  float t2 = t * t, t3 = t2 * t;
  c0 = -0.5f * t3 + t2 - 0.5f * t;
  c1 = 1.5f * t3 - 2.5f * t2 + 1.0f;
  c2 = -1.5f * t3 + 2.0f * t2 + 0.5f * t;
  c3 = 0.5f * t3 - 0.5f * t2;
}

// ---- prepass 1: Wb[o][i] = catmull_rom(cp)(o,i) + residual[o][i], as bf16 ----
__global__ void build_w(const float* __restrict__ cp, const float* __restrict__ resid,
                        unsigned short* __restrict__ wb) {
  int idx = blockIdx.x * 256 + threadIdx.x;  // one group of 4 elements
  int o = idx >> 10;                          // 1024 float4-groups per row
  int g = idx & 1023;
  int j; float c0, c1, c2, c3;
  cr_coeffs(o, j, c0, c1, c2, c3);
  const float4* cpv = (const float4*)cp;
  int base = (j - 1) * 1024 + g;
  float4 p0 = cpv[base];
  float4 p1 = cpv[base + 1024];
  float4 p2 = cpv[base + 2048];
  float4 p3 = cpv[base + 3072];
  float4 r = ((const float4*)resid)[idx];
  float w0 = c0 * p0.x + c1 * p1.x + c2 * p2.x + c3 * p3.x + r.x;
  float w1 = c0 * p0.y + c1 * p1.y + c2 * p2.y + c3 * p3.y + r.y;
  float w2 = c0 * p0.z + c1 * p1.z + c2 * p2.z + c3 * p3.z + r.z;
  float w3 = c0 * p0.w + c1 * p1.w + c2 * p2.w + c3 * p3.w + r.w;
  union { unsigned short s[4]; uint2 u; } pk;
  pk.s[0] = f2bf(w0); pk.s[1] = f2bf(w1); pk.s[2] = f2bf(w2); pk.s[3] = f2bf(w3);
  ((uint2*)wb)[idx] = pk.u;
}

// ---- prepass 2: x fp32 -> bf16 (8 elems/thread) ----
__global__ void convert_x(const float* __restrict__ x, unsigned short* __restrict__ xb) {
  int i = blockIdx.x * 256 + threadIdx.x;
  const float4* xv = (const float4*)x;
  float4 v0 = xv[2 * i], v1 = xv[2 * i + 1];
  union { unsigned short s[8]; uint4 u; } pk;
  pk.s[0] = f2bf(v0.x); pk.s[1] = f2bf(v0.y); pk.s[2] = f2bf(v0.z); pk.s[3] = f2bf(v0.w);
  pk.s[4] = f2bf(v1.x); pk.s[5] = f2bf(v1.y); pk.s[6] = f2bf(v1.z); pk.s[7] = f2bf(v1.w);
  ((uint4*)xb)[i] = pk.u;
}

// ---- main: C[M][N] = A[M][K] * B[N][K]^T + bias, bf16 inputs, fp32 out ----
// 128x128 tile, BK=64, 4 waves (2x2), mfma_f32_16x16x32_bf16.
// LDS XOR swizzle (16B slot ^= row&7) applied on BOTH sides: pre-swizzled
// global source for global_load_lds (linear dest) + swizzled ds_read.
__global__ void gemm_bt(const unsigned short* __restrict__ A,
                        const unsigned short* __restrict__ B,
                        const float* __restrict__ bias,
                        float* __restrict__ C) {
  __shared__ unsigned short As[128 * 64];
  __shared__ unsigned short Bs[128 * 64];

  const int tid = threadIdx.x;
  const int lane = tid & 63;
  const int wave = tid >> 6;
  const int wr = wave >> 1;   // wave row (2x2 grid of 64x64 wave tiles)
  const int wc = wave & 1;
  const int l15 = lane & 15;
  const int l4 = lane >> 4;

  const int bm = blockIdx.x >> 5;   // N/128 = 32 tiles per m-row
  const int bn = blockIdx.x & 31;
  const size_t row0 = (size_t)bm * 128;
  const size_t col0 = (size_t)bn * 128;

  floatx4 acc[4][4] = {};

  for (int kt = 0; kt < IN_F / 64; ++kt) {
    const int k0 = kt * 64;
    // stage 128x64 bf16 tiles of A and B; each wave-issue fills 1KB linearly
    #pragma unroll
    for (int q = 0; q < 4; ++q) {
      const int issue = q * 4 + wave;
      const int ofs16 = issue * 64 + lane;        // 16B-slot index in tile
      const int r = ofs16 >> 3;                    // row (8 slots of 16B per row)
      const int sl = (ofs16 & 7) ^ (r & 7);        // inverse-swizzled logical slot
      const unsigned short* ga = A + (row0 + r) * IN_F + k0 + sl * 8;
      const unsigned short* gb = B + (col0 + r) * IN_F + k0 + sl * 8;
      __builtin_amdgcn_global_load_lds(
          (const __attribute__((address_space(1))) void*)ga,
          (__attribute__((address_space(3))) void*)(As + issue * 512), 16, 0, 0);
      __builtin_amdgcn_global_load_lds(
          (const __attribute__((address_space(1))) void*)gb,
          (__attribute__((address_space(3))) void*)(Bs + issue * 512), 16, 0, 0);
    }
    __syncthreads();   // compiler emits vmcnt(0) drain before barrier

    #pragma unroll
    for (int kk = 0; kk < 2; ++kk) {
      short8 af[4], bf[4];
      #pragma unroll
      for (int m = 0; m < 4; ++m) {
        const int rr = wr * 64 + m * 16 + l15;
        const int slot = (kk * 4 + l4) ^ (rr & 7);
        af[m] = *(const short8*)(As + rr * 64 + slot * 8);
      }
      #pragma unroll
      for (int n = 0; n < 4; ++n) {
        const int rr = wc * 64 + n * 16 + l15;
        const int slot = (kk * 4 + l4) ^ (rr & 7);
        bf[n] = *(const short8*)(Bs + rr * 64 + slot * 8);
      }
      #pragma unroll
      for (int m = 0; m < 4; ++m)
        #pragma unroll
        for (int n = 0; n < 4; ++n)
          acc[m][n] = __builtin_amdgcn_mfma_f32_16x16x32_bf16(af[m], bf[n], acc[m][n], 0, 0, 0);
    }
    __syncthreads();
  }

  // epilogue: C = acc + bias. D layout: row=(lane>>4)*4+reg, col=lane&15
  #pragma unroll
  for (int n = 0; n < 4; ++n) {
    const size_t col = col0 + wc * 64 + n * 16 + l15;
    const float bv = bias[col];
    #pragma unroll
    for (int m = 0; m < 4; ++m) {
      const size_t row = row0 + wr * 64 + m * 16 + l4 * 4;
      #pragma unroll
      for (int r = 0; r < 4; ++r)
        C[(row + r) * OUT_F + col] = acc[m][n][r] + bv;
    }
  }
}

// ---- safety net if ws is too small: fp32 tiled GEMM w/ on-the-fly weight ----
__global__ void fallback_gemm(const float* __restrict__ x, const float* __restrict__ cp,
                              const float* __restrict__ resid, const float* __restrict__ bias,
                              float* __restrict__ out) {
  __shared__ float xs[64][32];
  __shared__ float ws[64][33];
  const int tid = threadIdx.x;
  const int bm = blockIdx.x / (OUT_F / 64);
  const int bn = blockIdx.x % (OUT_F / 64);
  const int row0 = bm * 64, col0 = bn * 64;
  const int tr = tid >> 4, tc = tid & 15;
  float acc[4][4] = {};
  for (int k0 = 0; k0 < IN_F; k0 += 32) {
    #pragma unroll
    for (int q = 0; q < 8; ++q) {
      int e = q * 256 + tid;
      int r = e >> 5, c = e & 31;
      xs[r][c] = x[(size_t)(row0 + r) * IN_F + k0 + c];
      int o = col0 + r;
      int j; float c0, c1, c2, c3;
      cr_coeffs(o, j, c0, c1, c2, c3);
      size_t ci = (size_t)(j - 1) * IN_F + k0 + c;
      ws[r][c] = c0 * cp[ci] + c1 * cp[ci + IN_F] + c2 * cp[ci + 2 * IN_F] +
                 c3 * cp[ci + 3 * IN_F] + resid[(size_t)o * IN_F + k0 + c];
    }
    __syncthreads();
    #pragma unroll
    for (int kk = 0; kk < 32; ++kk) {
      float xv[4], wv[4];
      #pragma unroll
      for (int i = 0; i < 4; ++i) xv[i] = xs[tr * 4 + i][kk];
      #pragma unroll
      for (int i = 0; i < 4; ++i) wv[i] = ws[tc * 4 + i][kk];
      #pragma unroll
      for (int i = 0; i < 4; ++i)
        #pragma unroll
        for (int jj = 0; jj < 4; ++jj) acc[i][jj] += xv[i] * wv[jj];
    }
    __syncthreads();
  }
  #pragma unroll
  for (int i = 0; i < 4; ++i)
    #pragma unroll
    for (int jj = 0; jj < 4; ++jj) {
      int row = row0 + tr * 4 + i, col = col0 + tc * 4 + jj;
      out[(size_t)row * OUT_F + col] = acc[i][jj] + bias[col];
    }
}

extern "C" void kernel_launch(void* const* d_in, const int* in_sizes, int n_in,
                              void* d_out, int out_size, void* d_ws, size_t ws_size,
                              hipStream_t stream) {
  const float* x = (const float*)d_in[0];
  const float* cp = (const float*)d_in[1];
  const float* resid = (const float*)d_in[2];
  const float* bias = (const float*)d_in[3];
  float* out = (float*)d_out;

  const size_t wb_bytes = (size_t)OUT_F * IN_F * 2;   // 33,554,432
  const size_t xb_bytes = (size_t)NROWS * IN_F * 2;   // 67,108,864

  if (ws_size >= wb_bytes + xb_bytes) {
    unsigned short* wb = (unsigned short*)d_ws;
    unsigned short* xb = (unsigned short*)((char*)d_ws + wb_bytes);
    // 16.7M/4 elems, 256 thr, 4 elems/thread -> 16384 blocks
    hipLaunchKernelGGL(build_w, dim3(16384), dim3(256), 0, stream, cp, resid, wb);
    // 33.5M/8 elems/thread -> 16384 blocks
    hipLaunchKernelGGL(convert_x, dim3(16384), dim3(256), 0, stream, x, xb);
    // (8192/128)*(4096/128) = 2048 blocks
    hipLaunchKernelGGL(gemm_bt, dim3(2048), dim3(256), 0, stream, xb, wb, bias, out);
  } else {
    hipLaunchKernelGGL(fallback_gemm, dim3((NROWS / 64) * (OUT_F / 64)), dim3(256), 0,
                       stream, x, cp, resid, bias, out);
  }
}

// Round 2
// 291.363 us; speedup vs baseline: 1.0188x; 1.0188x over previous
//
#include <hip/hip_runtime.h>
#include <stdint.h>

#define IN_F 4096
#define OUT_F 4096
#define NROWS 8192

#define BM 256
#define BN 256
#define BK 64
#define NT (IN_F / BK)   // 64 K-tiles

typedef __attribute__((ext_vector_type(8))) short short8;
typedef __attribute__((ext_vector_type(4))) float floatx4;

static __device__ __forceinline__ unsigned short f2bf(float f) {
  union { float f; unsigned int u; } v; v.f = f;
  unsigned int u = v.u;
  return (unsigned short)((u + 0x7FFFu + ((u >> 16) & 1u)) >> 16);
}

static __device__ __forceinline__ void cr_coeffs(int o, int& j, float& c0, float& c1,
                                                 float& c2, float& c3) {
  float ts = ((float)o / 4095.0f) * 8.0f;
  j = (int)floorf(ts);
  j = j < 1 ? 1 : (j > 6 ? 6 : j);
  float t = ts - (float)j;
  float t2 = t * t, t3 = t2 * t;
  c0 = -0.5f * t3 + t2 - 0.5f * t;
  c1 = 1.5f * t3 - 2.5f * t2 + 1.0f;
  c2 = -1.5f * t3 + 2.0f * t2 + 0.5f * t;
  c3 = 0.5f * t3 - 0.5f * t2;
}

// ---- prepass 1: Wb[o][i] = catmull_rom(cp)(o,i) + residual[o][i], as bf16 ----
__global__ void build_w(const float* __restrict__ cp, const float* __restrict__ resid,
                        unsigned short* __restrict__ wb) {
  int idx = blockIdx.x * 256 + threadIdx.x;
  int o = idx >> 10;
  int g = idx & 1023;
  int j; float c0, c1, c2, c3;
  cr_coeffs(o, j, c0, c1, c2, c3);
  const float4* cpv = (const float4*)cp;
  int base = (j - 1) * 1024 + g;
  float4 p0 = cpv[base];
  float4 p1 = cpv[base + 1024];
  float4 p2 = cpv[base + 2048];
  float4 p3 = cpv[base + 3072];
  float4 r = ((const float4*)resid)[idx];
  float w0 = c0 * p0.x + c1 * p1.x + c2 * p2.x + c3 * p3.x + r.x;
  float w1 = c0 * p0.y + c1 * p1.y + c2 * p2.y + c3 * p3.y + r.y;
  float w2 = c0 * p0.z + c1 * p1.z + c2 * p2.z + c3 * p3.z + r.z;
  float w3 = c0 * p0.w + c1 * p1.w + c2 * p2.w + c3 * p3.w + r.w;
  union { unsigned short s[4]; uint2 u; } pk;
  pk.s[0] = f2bf(w0); pk.s[1] = f2bf(w1); pk.s[2] = f2bf(w2); pk.s[3] = f2bf(w3);
  ((uint2*)wb)[idx] = pk.u;
}

// ---- prepass 2: x fp32 -> bf16 (8 elems/thread) ----
__global__ void convert_x(const float* __restrict__ x, unsigned short* __restrict__ xb) {
  int i = blockIdx.x * 256 + threadIdx.x;
  const float4* xv = (const float4*)x;
  float4 v0 = xv[2 * i], v1 = xv[2 * i + 1];
  union { unsigned short s[8]; uint4 u; } pk;
  pk.s[0] = f2bf(v0.x); pk.s[1] = f2bf(v0.y); pk.s[2] = f2bf(v0.z); pk.s[3] = f2bf(v0.w);
  pk.s[4] = f2bf(v1.x); pk.s[5] = f2bf(v1.y); pk.s[6] = f2bf(v1.z); pk.s[7] = f2bf(v1.w);
  ((uint4*)xb)[i] = pk.u;
}

#define MFMA_BF16(d, x, y) \
  d = __builtin_amdgcn_mfma_f32_16x16x32_bf16(x, y, d, 0, 0, 0)

// ---- main GEMM: 256x256 tile, BK=64, 8 waves, 8-phase schedule ----
// C[M][N] = A[M][K] * B[N][K]^T + bias.  LDS 16B-slot XOR swizzle (slot^=row&7)
// applied both-sides: pre-swizzled global source for global_load_lds (linear
// dest) + swizzled ds_read.  Counted vmcnt(6) per K-tile, never 0 mid-loop.
__global__ __launch_bounds__(512, 2) void gemm_8p(
    const unsigned short* __restrict__ A,
    const unsigned short* __restrict__ B,
    const float* __restrict__ bias,
    float* __restrict__ C) {
  __shared__ unsigned short lds[2][2][BM * BK];   // [buf][A/B][256*64] = 128 KiB

  const int tid = threadIdx.x;
  const int lane = tid & 63;
  const int wave = tid >> 6;   // 0..7
  const int wr = wave >> 2;    // 0..1  (M half)
  const int wc = wave & 3;     // 0..3  (N quarter)
  const int l15 = lane & 15;
  const int l4 = lane >> 4;

  const int bm = blockIdx.x >> 4;   // 32 M-tiles
  const int bn = blockIdx.x & 15;   // 16 N-tiles
  const size_t row0 = (size_t)bm * BM;
  const size_t col0 = (size_t)bn * BN;

  // stage 64 rows [r0, r0+64) of A (ab=0) or B (ab=1) tile, K-tile kt -> buf
  auto stage = [&](int buf, int ab, int r0, const unsigned short* __restrict__ src,
                   size_t grow0, int kt) {
    const int rr = tid >> 3;                       // 0..63
    const int sl = (tid & 7) ^ (rr & 7);           // inverse-swizzled logical slot
    const unsigned short* g = src + (grow0 + r0 + rr) * (size_t)IN_F + kt * BK + sl * 8;
    unsigned short* d = &lds[buf][ab][r0 * BK] + (tid >> 6) * 512;  // wave-uniform base
    __builtin_amdgcn_global_load_lds(
        (const __attribute__((address_space(1))) void*)g,
        (__attribute__((address_space(3))) void*)d, 16, 0, 0);
  };
  auto ldA = [&](int buf, int aq, int m, int kk) -> short8 {
    const int r = wr * 128 + aq * 64 + m * 16 + l15;
    const int slot = (kk * 4 + l4) ^ (r & 7);
    return *(const short8*)&lds[buf][0][r * BK + slot * 8];
  };
  auto ldB = [&](int buf, int n, int kk) -> short8 {
    const int r = wc * 64 + n * 16 + l15;
    const int slot = (kk * 4 + l4) ^ (r & 7);
    return *(const short8*)&lds[buf][1][r * BK + slot * 8];
  };

  floatx4 acc[8][4] = {};
  short8 a[4][2], b[4][2];

  // ---- prologue: kt0 complete (4 half-tile pairs), kt1 A0A2+B01+B23 ----
  stage(0, 0, 0,   A, row0, 0);  stage(0, 0, 128, A, row0, 0);   // kt0 A0,A2
  stage(0, 1, 0,   B, col0, 0);  stage(0, 1, 64,  B, col0, 0);   // kt0 B0,B1
  stage(0, 1, 128, B, col0, 0);  stage(0, 1, 192, B, col0, 0);   // kt0 B2,B3
  stage(0, 0, 64,  A, row0, 0);  stage(0, 0, 192, A, row0, 0);   // kt0 A1,A3
  stage(1, 0, 0,   A, row0, 1);  stage(1, 0, 128, A, row0, 1);   // kt1 A0,A2
  stage(1, 1, 0,   B, col0, 1);  stage(1, 1, 64,  B, col0, 1);   // kt1 B0,B1
  stage(1, 1, 128, B, col0, 1);  stage(1, 1, 192, B, col0, 1);   // kt1 B2,B3
  asm volatile("s_waitcnt vmcnt(6)" ::: "memory");   // kt0's 8 issues landed
  __builtin_amdgcn_s_barrier();

  for (int kt = 0; kt < NT; ++kt) {
    const int c = kt & 1, o = c ^ 1;

    // ---- P1: read A-quarter0 + B n0,n1 ; stage A1A3(kt+1) -> other buf ----
    #pragma unroll
    for (int m = 0; m < 4; ++m) { a[m][0] = ldA(c, 0, m, 0); a[m][1] = ldA(c, 0, m, 1); }
    #pragma unroll
    for (int n = 0; n < 2; ++n) { b[n][0] = ldB(c, n, 0); b[n][1] = ldB(c, n, 1); }
    if (kt + 1 < NT) { stage(o, 0, 64, A, row0, kt + 1); stage(o, 0, 192, A, row0, kt + 1); }
    __builtin_amdgcn_s_barrier();
    asm volatile("s_waitcnt lgkmcnt(0)" ::: "memory");
    __builtin_amdgcn_s_setprio(1);
    #pragma unroll
    for (int m = 0; m < 4; ++m)
      #pragma unroll
      for (int n = 0; n < 2; ++n) {
        MFMA_BF16(acc[m][n], a[m][0], b[n][0]);
        MFMA_BF16(acc[m][n], a[m][1], b[n][1]);
      }
    __builtin_amdgcn_s_setprio(0);
    __builtin_amdgcn_s_barrier();

    // ---- P2: read B n2,n3 ; stage A0A2(kt+2) (region freed at P1) ----
    #pragma unroll
    for (int n = 2; n < 4; ++n) { b[n][0] = ldB(c, n, 0); b[n][1] = ldB(c, n, 1); }
    if (kt + 2 < NT) { stage(c, 0, 0, A, row0, kt + 2); stage(c, 0, 128, A, row0, kt + 2); }
    __builtin_amdgcn_s_barrier();
    asm volatile("s_waitcnt lgkmcnt(0)" ::: "memory");
    __builtin_amdgcn_s_setprio(1);
    #pragma unroll
    for (int m = 0; m < 4; ++m)
      #pragma unroll
      for (int n = 2; n < 4; ++n) {
        MFMA_BF16(acc[m][n], a[m][0], b[n][0]);
        MFMA_BF16(acc[m][n], a[m][1], b[n][1]);
      }
    __builtin_amdgcn_s_setprio(0);
    __builtin_amdgcn_s_barrier();

    // ---- P3: read A-quarter1 (overwrite a-regs) ; stage B0B1(kt+2) ----
    #pragma unroll
    for (int m = 0; m < 4; ++m) { a[m][0] = ldA(c, 1, m, 0); a[m][1] = ldA(c, 1, m, 1); }
    if (kt + 2 < NT) { stage(c, 1, 0, B, col0, kt + 2); stage(c, 1, 64, B, col0, kt + 2); }
    __builtin_amdgcn_s_barrier();
    asm volatile("s_waitcnt lgkmcnt(0)" ::: "memory");
    __builtin_amdgcn_s_setprio(1);
    #pragma unroll
    for (int m = 0; m < 4; ++m)
      #pragma unroll
      for (int n = 2; n < 4; ++n) {
        MFMA_BF16(acc[4 + m][n], a[m][0], b[n][0]);
        MFMA_BF16(acc[4 + m][n], a[m][1], b[n][1]);
      }
    __builtin_amdgcn_s_setprio(0);
    __builtin_amdgcn_s_barrier();

    // ---- P4: stage B2B3(kt+2) ; counted vmcnt ; MFMA quarter1 x n0,n1 ----
    if (kt + 2 < NT) {
      stage(c, 1, 128, B, col0, kt + 2); stage(c, 1, 192, B, col0, kt + 2);
      asm volatile("s_waitcnt vmcnt(6)" ::: "memory");  // forces all kt+1 data landed
    } else {
      asm volatile("s_waitcnt vmcnt(0)" ::: "memory");  // tail: no kt+2 stages in flight
    }
    __builtin_amdgcn_s_barrier();
    __builtin_amdgcn_s_setprio(1);
    #pragma unroll
    for (int m = 0; m < 4; ++m)
      #pragma unroll
      for (int n = 0; n < 2; ++n) {
        MFMA_BF16(acc[4 + m][n], a[m][0], b[n][0]);   // b[0],b[1] still live from P1
        MFMA_BF16(acc[4 + m][n], a[m][1], b[n][1]);
      }
    __builtin_amdgcn_s_setprio(0);
    __builtin_amdgcn_s_barrier();
  }

  // ---- epilogue: C = acc + bias.  D layout: row=(lane>>4)*4+r, col=lane&15 ----
  #pragma unroll
  for (int n = 0; n < 4; ++n) {
    const size_t col = col0 + wc * 64 + n * 16 + l15;
    const float bv = bias[col];
    #pragma unroll
    for (int m = 0; m < 8; ++m) {
      const size_t rw = row0 + wr * 128 + m * 16 + l4 * 4;
      #pragma unroll
      for (int r = 0; r < 4; ++r)
        C[(rw + r) * OUT_F + col] = acc[m][n][r] + bv;
    }
  }
}

// ---- safety net if ws is too small: fp32 tiled GEMM w/ on-the-fly weight ----
__global__ void fallback_gemm(const float* __restrict__ x, const float* __restrict__ cp,
                              const float* __restrict__ resid, const float* __restrict__ bias,
                              float* __restrict__ out) {
  __shared__ float xs[64][32];
  __shared__ float ws[64][33];
  const int tid = threadIdx.x;
  const int bm = blockIdx.x / (OUT_F / 64);
  const int bn = blockIdx.x % (OUT_F / 64);
  const int row0 = bm * 64, col0 = bn * 64;
  const int tr = tid >> 4, tc = tid & 15;
  float acc[4][4] = {};
  for (int k0 = 0; k0 < IN_F; k0 += 32) {
    #pragma unroll
    for (int q = 0; q < 8; ++q) {
      int e = q * 256 + tid;
      int r = e >> 5, cc = e & 31;
      xs[r][cc] = x[(size_t)(row0 + r) * IN_F + k0 + cc];
      int o = col0 + r;
      int j; float c0, c1, c2, c3;
      cr_coeffs(o, j, c0, c1, c2, c3);
      size_t ci = (size_t)(j - 1) * IN_F + k0 + cc;
      ws[r][cc] = c0 * cp[ci] + c1 * cp[ci + IN_F] + c2 * cp[ci + 2 * IN_F] +
                  c3 * cp[ci + 3 * IN_F] + resid[(size_t)o * IN_F + k0 + cc];
    }
    __syncthreads();
    #pragma unroll
    for (int kk = 0; kk < 32; ++kk) {
      float xv[4], wv[4];
      #pragma unroll
      for (int i = 0; i < 4; ++i) xv[i] = xs[tr * 4 + i][kk];
      #pragma unroll
      for (int i = 0; i < 4; ++i) wv[i] = ws[tc * 4 + i][kk];
      #pragma unroll
      for (int i = 0; i < 4; ++i)
        #pragma unroll
        for (int jj = 0; jj < 4; ++jj) acc[i][jj] += xv[i] * wv[jj];
    }
    __syncthreads();
  }
  #pragma unroll
  for (int i = 0; i < 4; ++i)
    #pragma unroll
    for (int jj = 0; jj < 4; ++jj) {
      int row = row0 + tr * 4 + i, col = col0 + tc * 4 + jj;
      out[(size_t)row * OUT_F + col] = acc[i][jj] + bias[col];
    }
}

extern "C" void kernel_launch(void* const* d_in, const int* in_sizes, int n_in,
                              void* d_out, int out_size, void* d_ws, size_t ws_size,
                              hipStream_t stream) {
  const float* x = (const float*)d_in[0];
  const float* cp = (const float*)d_in[1];
  const float* resid = (const float*)d_in[2];
  const float* bias = (const float*)d_in[3];
  float* out = (float*)d_out;

  const size_t wb_bytes = (size_t)OUT_F * IN_F * 2;
  const size_t xb_bytes = (size_t)NROWS * IN_F * 2;

  if (ws_size >= wb_bytes + xb_bytes) {
    unsigned short* wb = (unsigned short*)d_ws;
    unsigned short* xb = (unsigned short*)((char*)d_ws + wb_bytes);
    hipLaunchKernelGGL(build_w, dim3(16384), dim3(256), 0, stream, cp, resid, wb);
    hipLaunchKernelGGL(convert_x, dim3(16384), dim3(256), 0, stream, x, xb);
    // (8192/256) * (4096/256) = 32*16 = 512 blocks, 512 threads
    hipLaunchKernelGGL(gemm_8p, dim3(512), dim3(512), 0, stream, xb, wb, bias, out);
  } else {
    hipLaunchKernelGGL(fallback_gemm, dim3((NROWS / 64) * (OUT_F / 64)), dim3(256), 0,
                       stream, x, cp, resid, bias, out);
  }
}